// Round 1
// baseline (271.934 us; speedup 1.0000x reference)
//
#include <hip/hip_runtime.h>
#include <cstdint>
#include <cstddef>

#define DD 128
#define KK 32
constexpr float EPS = 1e-8f;

typedef __bf16 bf16x8 __attribute__((ext_vector_type(8)));
typedef float f32x4 __attribute__((ext_vector_type(4)));

__device__ __forceinline__ unsigned short f2bf(float x) {
    union { float f; uint32_t u; } v; v.f = x;
    uint32_t r = v.u + 0x7FFFu + ((v.u >> 16) & 1u);   // RNE
    return (unsigned short)(r >> 16);
}
// pack 8 floats -> 8 bf16 in a uint4 (one 16B store)
__device__ __forceinline__ uint4 pack8(float4 a, float4 b) {
    uint4 o;
    o.x = (uint32_t)f2bf(a.x) | ((uint32_t)f2bf(a.y) << 16);
    o.y = (uint32_t)f2bf(a.z) | ((uint32_t)f2bf(a.w) << 16);
    o.z = (uint32_t)f2bf(b.x) | ((uint32_t)f2bf(b.y) << 16);
    o.w = (uint32_t)f2bf(b.z) | ((uint32_t)f2bf(b.w) << 16);
    return o;
}

// DPP quad_perm fold over lane-xor 1,2 (VALU pipe, no LDS).
template <int CTRL>
__device__ __forceinline__ float dpp_fold(float x) {
    union { float f; int i; } u, r;
    u.f = x;
    r.i = __builtin_amdgcn_update_dpp(0, u.i, CTRL, 0xF, 0xF, false);
    return x + r.f;
}
__device__ __forceinline__ f32x4 fold4(f32x4 v) {
    #pragma unroll
    for (int c = 0; c < 4; ++c) {
        float x = v[c];
        x = dpp_fold<0xB1>(x);   // xor 1
        x = dpp_fold<0x4E>(x);   // xor 2
        v[c] = x;
    }
    return v;
}

// ---------------- prep kernel: part2-GEMV (f32) + cvt + wf in ONE dispatch --
// Grid layout: [0, ngemv)                         : part2 GEMV blocks
//              [ngemv, ngemv+2*cvt_half)          : X f32->bf16 swizzle blocks
//              [.., +2*wf_half)                   : W f32->bf16 swizzle blocks
// GEMV reads the RAW f32 x1/x2 (no dependency on the cvt outputs), so it can
// share the dispatch. 8 rows x 32 k per block; f32 math (more accurate than
// the old bf16-MFMA part2). GEMV blocks first: longest per-block latency.
__global__ __launch_bounds__(256) void prep_kernel(
    const float* __restrict__ x1, const float* __restrict__ x2,
    const float* __restrict__ W1, const float* __restrict__ W2,
    const float* __restrict__ V,  float* __restrict__ p2w,
    __bf16* __restrict__ X1f, __bf16* __restrict__ X2f,
    __bf16* __restrict__ W1f, __bf16* __restrict__ W2f,
    int ngemv, int cvt_half, int wf_half)
{
    __shared__ float tile[16][132];    // 8.4 KB (cvt path)
    __shared__ float xrow[8][260];     // 8.3 KB (gemv path): [x1 row | x2 row]

    int bb = blockIdx.x;
    const int tid = threadIdx.x;

    if (bb < ngemv) {
        // -------- part2 GEMV: p2w[n][k] = cat(x1[n],x2[n]) . V[k] --------
        const int rb = bb * 8;   // 8 rows per block
        #pragma unroll
        for (int i = 0; i < 2; ++i) {
            int idx = tid + i * 256;        // float4 slot 0..511
            int row = idx >> 6;             // 64 float4 per 256-wide row
            int col = idx & 63;
            const float* src = (col < 32)
                ? (x1 + (size_t)(rb + row) * DD + col * 4)
                : (x2 + (size_t)(rb + row) * DD + (col - 32) * 4);
            *reinterpret_cast<float4*>(&xrow[row][col * 4]) =
                *reinterpret_cast<const float4*>(src);
        }
        __syncthreads();
        const int k   = tid & 31;
        const int row = tid >> 5;
        const float* Vk = V + (size_t)k * 256;
        float acc = 0.f;
        #pragma unroll 8
        for (int c = 0; c < 64; ++c) {
            float4 v  = *reinterpret_cast<const float4*>(Vk + c * 4);
            float4 xv = *reinterpret_cast<const float4*>(&xrow[row][c * 4]);
            acc += xv.x * v.x + xv.y * v.y + xv.z * v.z + xv.w * v.w;
        }
        p2w[(size_t)(rb + row) * KK + k] = acc;
        return;
    }
    bb -= ngemv;

    if (bb < 2 * cvt_half) {
        // -------- X f32 -> bf16 swizzled: Xf off = rg*2048 + c*128 + mm*8 ----
        const float* src; __bf16* dst;
        if (bb >= cvt_half) { src = x2; dst = X2f; bb -= cvt_half; }
        else                { src = x1; dst = X1f; }
        const int rg = bb;
        {
            const int row = tid >> 4;
            const int c8  = (tid & 15) * 8;
            const float* p = src + (size_t)(rg * 16 + row) * DD + c8;
            float4 f0 = *reinterpret_cast<const float4*>(p);
            float4 f1 = *reinterpret_cast<const float4*>(p + 4);
            *reinterpret_cast<float4*>(&tile[row][c8])     = f0;
            *reinterpret_cast<float4*>(&tile[row][c8 + 4]) = f1;
        }
        __syncthreads();
        {
            const int mm = tid & 15;
            const int c  = tid >> 4;
            float4 a = *reinterpret_cast<float4*>(&tile[mm][c * 8]);
            float4 b = *reinterpret_cast<float4*>(&tile[mm][c * 8 + 4]);
            size_t off = (size_t)rg * 2048 + (size_t)c * 128 + (size_t)mm * 8;
            *reinterpret_cast<uint4*>(dst + off) = pack8(a, b);
        }
    } else {
        // -------- W f32 -> bf16 swizzled: Wf[k][eg][c][mm][8] ----------------
        bb -= 2 * cvt_half;
        const float* W; __bf16* Wf;
        if (bb >= wf_half) { W = W2; Wf = W2f; bb -= wf_half; }
        else               { W = W1; Wf = W1f; }
        int idx = bb * 256 + tid;
        int mm = idx & 15;
        int c  = (idx >> 4) & 15;
        int eg = (idx >> 8) & 7;
        int k  = idx >> 11;
        const float* Wk = W + (size_t)k * DD * DD;
        int e = eg * 16 + mm;
        float4 a, b;
        a.x = Wk[(size_t)(c * 8 + 0) * DD + e];
        a.y = Wk[(size_t)(c * 8 + 1) * DD + e];
        a.z = Wk[(size_t)(c * 8 + 2) * DD + e];
        a.w = Wk[(size_t)(c * 8 + 3) * DD + e];
        b.x = Wk[(size_t)(c * 8 + 4) * DD + e];
        b.y = Wk[(size_t)(c * 8 + 5) * DD + e];
        b.z = Wk[(size_t)(c * 8 + 6) * DD + e];
        b.w = Wk[(size_t)(c * 8 + 7) * DD + e];
        size_t off = ((size_t)(k * 8 + eg)) * 2048 + (size_t)c * 128 + (size_t)mm * 8;
        *reinterpret_cast<uint4*>(Wf + off) = pack8(a, b);
    }
}

// ---------------- main fused kernel: ONE barrier per block ------------------
// Grid 4096 = 32 k x 128 row-groups (256 rows). XCD decode: xcd=b&7,
// k=(b>>3)&31 fast, group per-XCD. Block = 4 waves, wave = (rh, eh):
// 16 rows x 64 cols of BOTH mats; B register-resident; A prefetched 1 tile
// ahead. Each tile's folded partials land in a per-tile LDS slice; a SINGLE
// __syncthreads after the whole g-loop lets waves drift (MFMA of one wave
// overlaps epilogue VALU of another), then all 256 threads emit all 256
// outputs. p2w value preloaded at kernel start (scatter fully hidden).
// T5: waves drift at different phases -> s_setprio(1) around the MFMA
// cluster biases the CU scheduler toward the matrix-pipe wave.
__global__ __launch_bounds__(256, 2) void ntn_main(
    const __bf16* __restrict__ X1f, const __bf16* __restrict__ X2f,
    const __bf16* __restrict__ W1f, const __bf16* __restrict__ W2f,
    const float* __restrict__ p2w, const float* __restrict__ bias,
    float* __restrict__ out, int grp_per_xcd)
{
    __shared__ __align__(16) float sRedAll[8][3][2][4][40];   // 30.7 KB

    const int b    = blockIdx.x;
    const int xcd  = b & 7;
    const int k    = (b >> 3) & 31;
    const int grpN = xcd * grp_per_xcd + (b >> 8);   // 256-row group
    const int tid  = threadIdx.x;
    const int wave = tid >> 6;
    const int lane = tid & 63;
    const int m    = lane & 15;
    const int quad = lane >> 4;
    const int rh   = wave & 1;      // row half of the 32-row tile
    const int eh   = wave >> 1;     // column half (64 cols)

    // ---- preload this thread's p2w value (n = grpN*256 + tid) ----
    const size_t nOut = (size_t)grpN * 256 + tid;
    const float p2v = p2w[nOut * KK + k];
    const float bk  = bias[k];

    const __bf16* W1p = W1f + (size_t)k * 16384;
    const __bf16* W2p = W2f + (size_t)k * 16384;

    // ---- cache BOTH B halves in registers: 2 mats x 4 ks x 4 et ----
    bf16x8 Bc[2][4][4];
    #pragma unroll
    for (int ks = 0; ks < 4; ++ks)
        #pragma unroll
        for (int et = 0; et < 4; ++et) {
            const size_t boff = (size_t)(eh * 4 + et) * 2048 + ks * 512 + lane * 8;
            Bc[0][ks][et] = *reinterpret_cast<const bf16x8*>(W1p + boff);
            Bc[1][ks][et] = *reinterpret_cast<const bf16x8*>(W2p + boff);
        }

    const int rg0 = grpN * 16;
    const size_t lane8 = (size_t)lane * 8;

    // ---- preload tile 0's A fragments ----
    bf16x8 a1[4], a2[4];
    {
        const size_t ab = (size_t)(rg0 + rh) * 2048 + lane8;
        #pragma unroll
        for (int ks = 0; ks < 4; ++ks) {
            a1[ks] = *reinterpret_cast<const bf16x8*>(X1f + ab + ks * 512);
            a2[ks] = *reinterpret_cast<const bf16x8*>(X2f + ab + ks * 512);
        }
    }

    #pragma unroll
    for (int g = 0; g < 8; ++g) {
        f32x4 acc[2][4];    // [mat][et]
        #pragma unroll
        for (int mat = 0; mat < 2; ++mat)
            #pragma unroll
            for (int et = 0; et < 4; ++et) acc[mat][et] = f32x4{0.f, 0.f, 0.f, 0.f};

        __builtin_amdgcn_s_setprio(1);
        #pragma unroll
        for (int ks = 0; ks < 4; ++ks) {
            #pragma unroll
            for (int et = 0; et < 4; ++et) {
                acc[0][et] = __builtin_amdgcn_mfma_f32_16x16x32_bf16(a1[ks], Bc[0][ks][et], acc[0][et], 0, 0, 0);
                acc[1][et] = __builtin_amdgcn_mfma_f32_16x16x32_bf16(a2[ks], Bc[1][ks][et], acc[1][et], 0, 0, 0);
            }
        }
        __builtin_amdgcn_s_setprio(0);

        // ---- prefetch tile g+1's A fragments ----
        if (g < 7) {
            const size_t ab = (size_t)(rg0 + (g + 1) * 2 + rh) * 2048 + lane8;
            #pragma unroll
            for (int ks = 0; ks < 4; ++ks) {
                a1[ks] = *reinterpret_cast<const bf16x8*>(X1f + ab + ks * 512);
                a2[ks] = *reinterpret_cast<const bf16x8*>(X2f + ab + ks * 512);
            }
        }

        // ---- in-register cross-mat products + DPP folds -> per-tile LDS ----
        f32x4 pd = {0.f, 0.f, 0.f, 0.f};
        f32x4 q1 = {0.f, 0.f, 0.f, 0.f};
        f32x4 q2 = {0.f, 0.f, 0.f, 0.f};
        #pragma unroll
        for (int et = 0; et < 4; ++et) {
            f32x4 c1 = acc[0][et];
            f32x4 c2 = acc[1][et];
            pd += c1 * c2;
            q1 += c1 * c1;
            q2 += c2 * c2;
        }
        pd = fold4(pd);
        q1 = fold4(q1);
        q2 = fold4(q2);

        if ((m & 3) == 0) {
            const int grp = m >> 2;
            const int rb  = rh * 16 + quad * 4;
            *reinterpret_cast<f32x4*>(&sRedAll[g][0][eh][grp][rb]) = pd;
            *reinterpret_cast<f32x4*>(&sRedAll[g][1][eh][grp][rb]) = q1;
            *reinterpret_cast<f32x4*>(&sRedAll[g][2][eh][grp][rb]) = q2;
        }
        // NO barrier here — waves drift through tiles independently.
    }

    __syncthreads();   // the ONLY barrier: all 8 tiles' partials visible

    // ---- output: thread t -> tile = t>>5, row = t&31 (n = grpN*256 + t) ----
    {
        const int tile = tid >> 5;
        const int row  = tid & 31;
        float dot = 0.f, s1 = 0.f, s2 = 0.f;
        #pragma unroll
        for (int e2 = 0; e2 < 2; ++e2)
            #pragma unroll
            for (int gg = 0; gg < 4; ++gg) {
                dot += sRedAll[tile][0][e2][gg][row];
                s1  += sRedAll[tile][1][e2][gg][row];
                s2  += sRedAll[tile][2][e2][gg][row];
            }
        float n1 = fmaxf(sqrtf(s1), EPS);
        float n2 = fmaxf(sqrtf(s2), EPS);
        float tot = dot / (n1 * n2) + p2v + bk;
        out[nOut * KK + k] = fmaxf(tot, 0.f);
    }
}

extern "C" void kernel_launch(void* const* d_in, const int* in_sizes, int n_in,
                              void* d_out, int out_size, void* d_ws, size_t ws_size,
                              hipStream_t stream) {
    const float* x1 = (const float*)d_in[0];
    const float* x2 = (const float*)d_in[1];
    const float* W1 = (const float*)d_in[2];
    const float* W2 = (const float*)d_in[3];
    const float* V  = (const float*)d_in[4];
    const float* b  = (const float*)d_in[5];
    float* out = (float*)d_out;

    const int N = in_sizes[0] / DD;   // 32768

    __bf16* X1f = (__bf16*)d_ws;
    __bf16* X2f = X1f + (size_t)N * DD;
    __bf16* W1f = X2f + (size_t)N * DD;
    __bf16* W2f = W1f + (size_t)KK * DD * DD;
    float*  p2w = (float*)(W2f + (size_t)KK * DD * DD);

    const int ngemv    = N / 8;                   // 4096 part2-GEMV blocks
    const int cvt_half = N / 16;                  // 2048 blocks per tensor
    const int wf_half  = KK * DD * DD / 8 / 256;  // 256
    prep_kernel<<<ngemv + 2 * cvt_half + 2 * wf_half, 256, 0, stream>>>(
        x1, x2, W1, W2, V, p2w, X1f, X2f, W1f, W2f, ngemv, cvt_half, wf_half);

    const int groups = N / 256;                   // 128
    ntn_main<<<groups * KK, 256, 0, stream>>>(X1f, X2f, W1f, W2f, p2w, b, out,
                                              groups / 8);
}

// Round 2
// 167.556 us; speedup vs baseline: 1.6229x; 1.6229x over previous
//
#include <hip/hip_runtime.h>
#include <cstdint>
#include <cstddef>

#define DD 128
#define KK 32
constexpr float EPS = 1e-8f;

typedef __bf16 bf16x8 __attribute__((ext_vector_type(8)));
typedef float f32x4 __attribute__((ext_vector_type(4)));

__device__ __forceinline__ unsigned short f2bf(float x) {
    union { float f; uint32_t u; } v; v.f = x;
    uint32_t r = v.u + 0x7FFFu + ((v.u >> 16) & 1u);   // RNE
    return (unsigned short)(r >> 16);
}
__device__ __forceinline__ __bf16 f2bf16(float x) {
    unsigned short u = f2bf(x);
    __bf16 r; __builtin_memcpy(&r, &u, 2); return r;
}
// pack 8 floats -> 8 bf16 in a uint4 (one 16B store)
__device__ __forceinline__ uint4 pack8(float4 a, float4 b) {
    uint4 o;
    o.x = (uint32_t)f2bf(a.x) | ((uint32_t)f2bf(a.y) << 16);
    o.y = (uint32_t)f2bf(a.z) | ((uint32_t)f2bf(a.w) << 16);
    o.z = (uint32_t)f2bf(b.x) | ((uint32_t)f2bf(b.y) << 16);
    o.w = (uint32_t)f2bf(b.z) | ((uint32_t)f2bf(b.w) << 16);
    return o;
}

// DPP quad_perm fold over lane-xor 1,2 (VALU pipe, no LDS).
template <int CTRL>
__device__ __forceinline__ float dpp_fold(float x) {
    union { float f; int i; } u, r;
    u.f = x;
    r.i = __builtin_amdgcn_update_dpp(0, u.i, CTRL, 0xF, 0xF, false);
    return x + r.f;
}
__device__ __forceinline__ f32x4 fold4(f32x4 v) {
    #pragma unroll
    for (int c = 0; c < 4; ++c) {
        float x = v[c];
        x = dpp_fold<0xB1>(x);   // xor 1
        x = dpp_fold<0x4E>(x);   // xor 2
        v[c] = x;
    }
    return v;
}

// ---------------- prep kernel (r13 proven, verbatim): cvt + wf ---------------
// Xf[rg][c][mm][8]: row = rg*16+mm, d = c*8+j  -> off = rg*2048 + c*128 + mm*8
// Wf[k][eg][c][mm][8]: W[k][d=c*8+j][e=eg*16+mm]
__global__ __launch_bounds__(256) void prep_kernel(
    const float* __restrict__ x1, const float* __restrict__ x2,
    const float* __restrict__ W1, const float* __restrict__ W2,
    __bf16* __restrict__ X1f, __bf16* __restrict__ X2f,
    __bf16* __restrict__ W1f, __bf16* __restrict__ W2f,
    int cvt_half, int wf_half)
{
    __shared__ float tile[16][132];   // 8.4 KB, +4 pad
    int bb = blockIdx.x;
    if (bb < 2 * cvt_half) {
        const float* src; __bf16* dst;
        if (bb >= cvt_half) { src = x2; dst = X2f; bb -= cvt_half; }
        else                { src = x1; dst = X1f; }
        const int rg = bb;
        {
            const int row = threadIdx.x >> 4;
            const int c8  = (threadIdx.x & 15) * 8;
            const float* p = src + (size_t)(rg * 16 + row) * DD + c8;
            float4 f0 = *reinterpret_cast<const float4*>(p);
            float4 f1 = *reinterpret_cast<const float4*>(p + 4);
            *reinterpret_cast<float4*>(&tile[row][c8])     = f0;
            *reinterpret_cast<float4*>(&tile[row][c8 + 4]) = f1;
        }
        __syncthreads();
        {
            const int mm = threadIdx.x & 15;
            const int c  = threadIdx.x >> 4;
            float4 a = *reinterpret_cast<float4*>(&tile[mm][c * 8]);
            float4 b = *reinterpret_cast<float4*>(&tile[mm][c * 8 + 4]);
            size_t off = (size_t)rg * 2048 + (size_t)c * 128 + (size_t)mm * 8;
            *reinterpret_cast<uint4*>(dst + off) = pack8(a, b);
        }
    } else {
        bb -= 2 * cvt_half;
        const float* W; __bf16* Wf;
        if (bb >= wf_half) { W = W2; Wf = W2f; bb -= wf_half; }
        else               { W = W1; Wf = W1f; }
        int idx = bb * 256 + threadIdx.x;
        int mm = idx & 15;
        int c  = (idx >> 4) & 15;
        int eg = (idx >> 8) & 7;
        int k  = idx >> 11;
        const float* Wk = W + (size_t)k * DD * DD;
        int e = eg * 16 + mm;
        float4 a, b;
        a.x = Wk[(size_t)(c * 8 + 0) * DD + e];
        a.y = Wk[(size_t)(c * 8 + 1) * DD + e];
        a.z = Wk[(size_t)(c * 8 + 2) * DD + e];
        a.w = Wk[(size_t)(c * 8 + 3) * DD + e];
        b.x = Wk[(size_t)(c * 8 + 4) * DD + e];
        b.y = Wk[(size_t)(c * 8 + 5) * DD + e];
        b.z = Wk[(size_t)(c * 8 + 6) * DD + e];
        b.w = Wk[(size_t)(c * 8 + 7) * DD + e];
        size_t off = ((size_t)(k * 8 + eg)) * 2048 + (size_t)c * 128 + (size_t)mm * 8;
        *reinterpret_cast<uint4*>(Wf + off) = pack8(a, b);
    }
}

// ---------------- main fused kernel: ONE barrier per block ------------------
// Grid 4096 = 32 k x 128 row-groups (256 rows). Block = 4 waves, wave =
// (rh, eh): 16 rows x 64 cols of BOTH mats; B register-resident; A prefetched
// 1 tile ahead. part2 (xcat.V[k]) is FUSED: a B-fragment built from V[k]
// with only output-column 0 nonzero (lanes m==0 carry V, others 0) adds
// 4 MFMAs/tile/wave: eh=0 waves accumulate x1.V[k][0:128], eh=1 waves
// x2.V[k][128:256]; column 0 of the result (lanes m==0) is the per-row dot,
// dropped into a 4 KB LDS slice and summed across eh in the epilogue.
// Single __syncthreads after the g-loop; waves drift (MFMA of one wave
// overlaps epilogue VALU of another).
__global__ __launch_bounds__(256, 2) void ntn_main(
    const __bf16* __restrict__ X1f, const __bf16* __restrict__ X2f,
    const __bf16* __restrict__ W1f, const __bf16* __restrict__ W2f,
    const float* __restrict__ V, const float* __restrict__ bias,
    float* __restrict__ out, int grp_per_xcd)
{
    __shared__ __align__(16) float sRedAll[8][3][2][4][40];   // 30.7 KB
    __shared__ __align__(16) float sP2[8][2][2][16];          //  4.0 KB

    const int b    = blockIdx.x;
    const int xcd  = b & 7;
    const int k    = (b >> 3) & 31;
    const int grpN = xcd * grp_per_xcd + (b >> 8);   // 256-row group
    const int tid  = threadIdx.x;
    const int wave = tid >> 6;
    const int lane = tid & 63;
    const int m    = lane & 15;
    const int quad = lane >> 4;
    const int rh   = wave & 1;      // row half of the 32-row tile
    const int eh   = wave >> 1;     // column half (64 cols)

    const size_t nOut = (size_t)grpN * 256 + tid;
    const float bk  = bias[k];

    const __bf16* W1p = W1f + (size_t)k * 16384;
    const __bf16* W2p = W2f + (size_t)k * 16384;

    // ---- cache BOTH B halves in registers: 2 mats x 4 ks x 4 et ----
    bf16x8 Bc[2][4][4];
    #pragma unroll
    for (int ks = 0; ks < 4; ++ks)
        #pragma unroll
        for (int et = 0; et < 4; ++et) {
            const size_t boff = (size_t)(eh * 4 + et) * 2048 + ks * 512 + lane * 8;
            Bc[0][ks][et] = *reinterpret_cast<const bf16x8*>(W1p + boff);
            Bc[1][ks][et] = *reinterpret_cast<const bf16x8*>(W2p + boff);
        }

    // ---- V B-fragment: only output-column 0 nonzero (lanes m==0) ----
    // eh=0 pairs with a1 (x1 part, V[k][0:128]); eh=1 with a2 (V[k][128:256]).
    bf16x8 Vb[4];
    {
        const float* Vk = V + (size_t)k * 256 + eh * 128 + quad * 8;
        #pragma unroll
        for (int ks = 0; ks < 4; ++ks) {
            float4 v0 = *reinterpret_cast<const float4*>(Vk + ks * 32);
            float4 v1 = *reinterpret_cast<const float4*>(Vk + ks * 32 + 4);
            bf16x8 t;
            t[0] = f2bf16(v0.x); t[1] = f2bf16(v0.y);
            t[2] = f2bf16(v0.z); t[3] = f2bf16(v0.w);
            t[4] = f2bf16(v1.x); t[5] = f2bf16(v1.y);
            t[6] = f2bf16(v1.z); t[7] = f2bf16(v1.w);
            if (m != 0) {
                #pragma unroll
                for (int j = 0; j < 8; ++j) t[j] = (__bf16)0.0f;
            }
            Vb[ks] = t;
        }
    }

    const int rg0 = grpN * 16;
    const size_t lane8 = (size_t)lane * 8;

    // ---- preload tile 0's A fragments ----
    bf16x8 a1[4], a2[4];
    {
        const size_t ab = (size_t)(rg0 + rh) * 2048 + lane8;
        #pragma unroll
        for (int ks = 0; ks < 4; ++ks) {
            a1[ks] = *reinterpret_cast<const bf16x8*>(X1f + ab + ks * 512);
            a2[ks] = *reinterpret_cast<const bf16x8*>(X2f + ab + ks * 512);
        }
    }

    #pragma unroll
    for (int g = 0; g < 8; ++g) {
        f32x4 acc[2][4];    // [mat][et]
        #pragma unroll
        for (int mat = 0; mat < 2; ++mat)
            #pragma unroll
            for (int et = 0; et < 4; ++et) acc[mat][et] = f32x4{0.f, 0.f, 0.f, 0.f};
        f32x4 accv = {0.f, 0.f, 0.f, 0.f};

        __builtin_amdgcn_s_setprio(1);
        #pragma unroll
        for (int ks = 0; ks < 4; ++ks) {
            #pragma unroll
            for (int et = 0; et < 4; ++et) {
                acc[0][et] = __builtin_amdgcn_mfma_f32_16x16x32_bf16(a1[ks], Bc[0][ks][et], acc[0][et], 0, 0, 0);
                acc[1][et] = __builtin_amdgcn_mfma_f32_16x16x32_bf16(a2[ks], Bc[1][ks][et], acc[1][et], 0, 0, 0);
            }
        }
        // part2 fused MFMAs (column 0 only carries data)
        if (eh == 0) {
            #pragma unroll
            for (int ks = 0; ks < 4; ++ks)
                accv = __builtin_amdgcn_mfma_f32_16x16x32_bf16(a1[ks], Vb[ks], accv, 0, 0, 0);
        } else {
            #pragma unroll
            for (int ks = 0; ks < 4; ++ks)
                accv = __builtin_amdgcn_mfma_f32_16x16x32_bf16(a2[ks], Vb[ks], accv, 0, 0, 0);
        }
        __builtin_amdgcn_s_setprio(0);

        // ---- prefetch tile g+1's A fragments ----
        if (g < 7) {
            const size_t ab = (size_t)(rg0 + (g + 1) * 2 + rh) * 2048 + lane8;
            #pragma unroll
            for (int ks = 0; ks < 4; ++ks) {
                a1[ks] = *reinterpret_cast<const bf16x8*>(X1f + ab + ks * 512);
                a2[ks] = *reinterpret_cast<const bf16x8*>(X2f + ab + ks * 512);
            }
        }

        // ---- in-register cross-mat products + DPP folds -> per-tile LDS ----
        f32x4 pd = {0.f, 0.f, 0.f, 0.f};
        f32x4 q1 = {0.f, 0.f, 0.f, 0.f};
        f32x4 q2 = {0.f, 0.f, 0.f, 0.f};
        #pragma unroll
        for (int et = 0; et < 4; ++et) {
            f32x4 c1 = acc[0][et];
            f32x4 c2 = acc[1][et];
            pd += c1 * c2;
            q1 += c1 * c1;
            q2 += c2 * c2;
        }
        pd = fold4(pd);
        q1 = fold4(q1);
        q2 = fold4(q2);

        if ((m & 3) == 0) {
            const int grp = m >> 2;
            const int rb  = rh * 16 + quad * 4;
            *reinterpret_cast<f32x4*>(&sRedAll[g][0][eh][grp][rb]) = pd;
            *reinterpret_cast<f32x4*>(&sRedAll[g][1][eh][grp][rb]) = q1;
            *reinterpret_cast<f32x4*>(&sRedAll[g][2][eh][grp][rb]) = q2;
        }
        // part2 dot lives in column 0 -> lanes m==0, row = quad*4+reg
        if (m == 0) {
            *reinterpret_cast<f32x4*>(&sP2[g][eh][rh][quad * 4]) = accv;
        }
        // NO barrier here — waves drift through tiles independently.
    }

    __syncthreads();   // the ONLY barrier: all 8 tiles' partials visible

    // ---- output: thread t -> tile = t>>5, row = t&31 (n = grpN*256 + t) ----
    {
        const int tile = tid >> 5;
        const int row  = tid & 31;
        const int rowh = row >> 4;
        const int rowl = row & 15;
        float dot = 0.f, s1 = 0.f, s2 = 0.f;
        #pragma unroll
        for (int e2 = 0; e2 < 2; ++e2)
            #pragma unroll
            for (int gg = 0; gg < 4; ++gg) {
                dot += sRedAll[tile][0][e2][gg][row];
                s1  += sRedAll[tile][1][e2][gg][row];
                s2  += sRedAll[tile][2][e2][gg][row];
            }
        float p2v = sP2[tile][0][rowh][rowl] + sP2[tile][1][rowh][rowl];
        float n1 = fmaxf(sqrtf(s1), EPS);
        float n2 = fmaxf(sqrtf(s2), EPS);
        float tot = dot / (n1 * n2) + p2v + bk;
        out[nOut * KK + k] = fmaxf(tot, 0.f);
    }
}

extern "C" void kernel_launch(void* const* d_in, const int* in_sizes, int n_in,
                              void* d_out, int out_size, void* d_ws, size_t ws_size,
                              hipStream_t stream) {
    const float* x1 = (const float*)d_in[0];
    const float* x2 = (const float*)d_in[1];
    const float* W1 = (const float*)d_in[2];
    const float* W2 = (const float*)d_in[3];
    const float* V  = (const float*)d_in[4];
    const float* b  = (const float*)d_in[5];
    float* out = (float*)d_out;

    const int N = in_sizes[0] / DD;   // 32768

    __bf16* X1f = (__bf16*)d_ws;
    __bf16* X2f = X1f + (size_t)N * DD;
    __bf16* W1f = X2f + (size_t)N * DD;
    __bf16* W2f = W1f + (size_t)KK * DD * DD;

    const int cvt_half = N / 16;                  // 2048 blocks per tensor
    const int wf_half  = KK * DD * DD / 8 / 256;  // 256
    prep_kernel<<<2 * cvt_half + 2 * wf_half, 256, 0, stream>>>(
        x1, x2, W1, W2, X1f, X2f, W1f, W2f, cvt_half, wf_half);

    const int groups = N / 256;                   // 128
    ntn_main<<<groups * KK, 256, 0, stream>>>(X1f, X2f, W1f, W2f, V, b, out,
                                              groups / 8);
}

// Round 3
// 165.065 us; speedup vs baseline: 1.6474x; 1.0151x over previous
//
#include <hip/hip_runtime.h>
#include <cstdint>
#include <cstddef>

#define DD 128
#define KK 32
constexpr float EPS = 1e-8f;

typedef __bf16 bf16x8 __attribute__((ext_vector_type(8)));
typedef float f32x4 __attribute__((ext_vector_type(4)));

__device__ __forceinline__ unsigned short f2bf(float x) {
    union { float f; uint32_t u; } v; v.f = x;
    uint32_t r = v.u + 0x7FFFu + ((v.u >> 16) & 1u);   // RNE
    return (unsigned short)(r >> 16);
}
__device__ __forceinline__ __bf16 f2bf16(float x) {
    unsigned short u = f2bf(x);
    __bf16 r; __builtin_memcpy(&r, &u, 2); return r;
}
// pack 8 floats -> 8 bf16 in a uint4 (one 16B store)
__device__ __forceinline__ uint4 pack8(float4 a, float4 b) {
    uint4 o;
    o.x = (uint32_t)f2bf(a.x) | ((uint32_t)f2bf(a.y) << 16);
    o.y = (uint32_t)f2bf(a.z) | ((uint32_t)f2bf(a.w) << 16);
    o.z = (uint32_t)f2bf(b.x) | ((uint32_t)f2bf(b.y) << 16);
    o.w = (uint32_t)f2bf(b.z) | ((uint32_t)f2bf(b.w) << 16);
    return o;
}

// DPP quad_perm fold over lane-xor 1,2 (VALU pipe, no LDS).
template <int CTRL>
__device__ __forceinline__ float dpp_fold(float x) {
    union { float f; int i; } u, r;
    u.f = x;
    r.i = __builtin_amdgcn_update_dpp(0, u.i, CTRL, 0xF, 0xF, false);
    return x + r.f;
}
__device__ __forceinline__ f32x4 fold4(f32x4 v) {
    #pragma unroll
    for (int c = 0; c < 4; ++c) {
        float x = v[c];
        x = dpp_fold<0xB1>(x);   // xor 1
        x = dpp_fold<0x4E>(x);   // xor 2
        v[c] = x;
    }
    return v;
}

// ---------------- prep kernel: cvt + wf + FUSED part2 -----------------------
// cvt blocks stage 16 rows of x (f32) in LDS anyway; waves 0,1 additionally
// compute this tensor-half's part2 contribution for those 16 rows:
//   p2[half][n][k] = x_half[n] . V[k][half*128 : half*128+128]
// via 4 MFMAs per wave (ct = wave = k-group of 16). B-frags built from L2-hot
// V; A-frags re-read from the LDS tile (2-way bank alias only). No race: each
// (half, 16-row group) is owned by exactly one block. ntn sums the 2 planes.
__global__ __launch_bounds__(256) void prep_kernel(
    const float* __restrict__ x1, const float* __restrict__ x2,
    const float* __restrict__ W1, const float* __restrict__ W2,
    const float* __restrict__ V,
    __bf16* __restrict__ X1f, __bf16* __restrict__ X2f,
    __bf16* __restrict__ W1f, __bf16* __restrict__ W2f,
    float* __restrict__ p2,            // [2][N*KK]
    int cvt_half, int wf_half)
{
    __shared__ float tile[16][132];   // 8.4 KB, +4 pad
    int bb = blockIdx.x;
    if (bb < 2 * cvt_half) {
        const float* src; __bf16* dst; int half;
        if (bb >= cvt_half) { src = x2; dst = X2f; half = 1; bb -= cvt_half; }
        else                { src = x1; dst = X1f; half = 0; }
        const int rg = bb;
        {
            const int row = threadIdx.x >> 4;
            const int c8  = (threadIdx.x & 15) * 8;
            const float* p = src + (size_t)(rg * 16 + row) * DD + c8;
            float4 f0 = *reinterpret_cast<const float4*>(p);
            float4 f1 = *reinterpret_cast<const float4*>(p + 4);
            *reinterpret_cast<float4*>(&tile[row][c8])     = f0;
            *reinterpret_cast<float4*>(&tile[row][c8 + 4]) = f1;
        }
        __syncthreads();
        {
            const int mm = threadIdx.x & 15;
            const int c  = threadIdx.x >> 4;
            float4 a = *reinterpret_cast<float4*>(&tile[mm][c * 8]);
            float4 b = *reinterpret_cast<float4*>(&tile[mm][c * 8 + 4]);
            size_t off = (size_t)rg * 2048 + (size_t)c * 128 + (size_t)mm * 8;
            *reinterpret_cast<uint4*>(dst + off) = pack8(a, b);
        }
        // ---- fused part2 half-dot: waves 0,1 only (ct = wave) ----
        const int wave = threadIdx.x >> 6;
        if (wave < 2) {
            const int lane = threadIdx.x & 63;
            const int m    = lane & 15;
            const int quad = lane >> 4;
            const int ct   = wave;
            bf16x8 a[4], bf[4];
            #pragma unroll
            for (int ks = 0; ks < 4; ++ks) {
                // A: row m, d = ks*32 + quad*8 .. +8 (from LDS tile, f32)
                float4 a0 = *reinterpret_cast<float4*>(&tile[m][ks * 32 + quad * 8]);
                float4 a1 = *reinterpret_cast<float4*>(&tile[m][ks * 32 + quad * 8 + 4]);
                bf16x8 t;
                t[0] = f2bf16(a0.x); t[1] = f2bf16(a0.y);
                t[2] = f2bf16(a0.z); t[3] = f2bf16(a0.w);
                t[4] = f2bf16(a1.x); t[5] = f2bf16(a1.y);
                t[6] = f2bf16(a1.z); t[7] = f2bf16(a1.w);
                a[ks] = t;
                // B: col k = ct*16+m, same d-range of this half of V
                const float* Vp = V + (size_t)(ct * 16 + m) * 256 + half * 128 + ks * 32 + quad * 8;
                float4 v0 = *reinterpret_cast<const float4*>(Vp);
                float4 v1 = *reinterpret_cast<const float4*>(Vp + 4);
                bf16x8 u;
                u[0] = f2bf16(v0.x); u[1] = f2bf16(v0.y);
                u[2] = f2bf16(v0.z); u[3] = f2bf16(v0.w);
                u[4] = f2bf16(v1.x); u[5] = f2bf16(v1.y);
                u[6] = f2bf16(v1.z); u[7] = f2bf16(v1.w);
                bf[ks] = u;
            }
            f32x4 acc = {0.f, 0.f, 0.f, 0.f};
            #pragma unroll
            for (int ks = 0; ks < 4; ++ks)
                acc = __builtin_amdgcn_mfma_f32_16x16x32_bf16(a[ks], bf[ks], acc, 0, 0, 0);
            float* p2h = p2 + (size_t)half * (size_t)cvt_half * 16 * KK;
            #pragma unroll
            for (int reg = 0; reg < 4; ++reg)
                p2h[(size_t)(rg * 16 + quad * 4 + reg) * KK + ct * 16 + m] = acc[reg];
        }
    } else {
        bb -= 2 * cvt_half;
        const float* W; __bf16* Wf;
        if (bb >= wf_half) { W = W2; Wf = W2f; bb -= wf_half; }
        else               { W = W1; Wf = W1f; }
        int idx = bb * 256 + threadIdx.x;
        int mm = idx & 15;
        int c  = (idx >> 4) & 15;
        int eg = (idx >> 8) & 7;
        int k  = idx >> 11;
        const float* Wk = W + (size_t)k * DD * DD;
        int e = eg * 16 + mm;
        float4 a, b;
        a.x = Wk[(size_t)(c * 8 + 0) * DD + e];
        a.y = Wk[(size_t)(c * 8 + 1) * DD + e];
        a.z = Wk[(size_t)(c * 8 + 2) * DD + e];
        a.w = Wk[(size_t)(c * 8 + 3) * DD + e];
        b.x = Wk[(size_t)(c * 8 + 4) * DD + e];
        b.y = Wk[(size_t)(c * 8 + 5) * DD + e];
        b.z = Wk[(size_t)(c * 8 + 6) * DD + e];
        b.w = Wk[(size_t)(c * 8 + 7) * DD + e];
        size_t off = ((size_t)(k * 8 + eg)) * 2048 + (size_t)c * 128 + (size_t)mm * 8;
        *reinterpret_cast<uint4*>(Wf + off) = pack8(a, b);
    }
}

// ---------------- main fused kernel: ONE barrier per block ------------------
// (r0 proven structure, 82.8 us) Grid 4096 = 32 k x 128 row-groups.
// Block = 4 waves, wave = (rh, eh): 16 rows x 64 cols of BOTH mats;
// B register-resident; A prefetched 1 tile ahead; per-tile folded partials in
// LDS; single barrier; p2 preloaded (sum of 2 half-planes).
__global__ __launch_bounds__(256, 2) void ntn_main(
    const __bf16* __restrict__ X1f, const __bf16* __restrict__ X2f,
    const __bf16* __restrict__ W1f, const __bf16* __restrict__ W2f,
    const float* __restrict__ p2, const float* __restrict__ bias,
    float* __restrict__ out, int grp_per_xcd, int plane)
{
    __shared__ __align__(16) float sRedAll[8][3][2][4][40];   // 30.7 KB

    const int b    = blockIdx.x;
    const int xcd  = b & 7;
    const int k    = (b >> 3) & 31;
    const int grpN = xcd * grp_per_xcd + (b >> 8);   // 256-row group
    const int tid  = threadIdx.x;
    const int wave = tid >> 6;
    const int lane = tid & 63;
    const int m    = lane & 15;
    const int quad = lane >> 4;
    const int rh   = wave & 1;      // row half of the 32-row tile
    const int eh   = wave >> 1;     // column half (64 cols)

    // ---- preload this thread's part2 value (n = grpN*256 + tid) ----
    const size_t nOut = (size_t)grpN * 256 + tid;
    const float p2v = p2[nOut * KK + k] + p2[nOut * KK + k + (size_t)plane];
    const float bk  = bias[k];

    const __bf16* W1p = W1f + (size_t)k * 16384;
    const __bf16* W2p = W2f + (size_t)k * 16384;

    // ---- cache BOTH B halves in registers: 2 mats x 4 ks x 4 et ----
    bf16x8 Bc[2][4][4];
    #pragma unroll
    for (int ks = 0; ks < 4; ++ks)
        #pragma unroll
        for (int et = 0; et < 4; ++et) {
            const size_t boff = (size_t)(eh * 4 + et) * 2048 + ks * 512 + lane * 8;
            Bc[0][ks][et] = *reinterpret_cast<const bf16x8*>(W1p + boff);
            Bc[1][ks][et] = *reinterpret_cast<const bf16x8*>(W2p + boff);
        }

    const int rg0 = grpN * 16;
    const size_t lane8 = (size_t)lane * 8;

    // ---- preload tile 0's A fragments ----
    bf16x8 a1[4], a2[4];
    {
        const size_t ab = (size_t)(rg0 + rh) * 2048 + lane8;
        #pragma unroll
        for (int ks = 0; ks < 4; ++ks) {
            a1[ks] = *reinterpret_cast<const bf16x8*>(X1f + ab + ks * 512);
            a2[ks] = *reinterpret_cast<const bf16x8*>(X2f + ab + ks * 512);
        }
    }

    #pragma unroll
    for (int g = 0; g < 8; ++g) {
        f32x4 acc[2][4];    // [mat][et]
        #pragma unroll
        for (int mat = 0; mat < 2; ++mat)
            #pragma unroll
            for (int et = 0; et < 4; ++et) acc[mat][et] = f32x4{0.f, 0.f, 0.f, 0.f};

        __builtin_amdgcn_s_setprio(1);
        #pragma unroll
        for (int ks = 0; ks < 4; ++ks) {
            #pragma unroll
            for (int et = 0; et < 4; ++et) {
                acc[0][et] = __builtin_amdgcn_mfma_f32_16x16x32_bf16(a1[ks], Bc[0][ks][et], acc[0][et], 0, 0, 0);
                acc[1][et] = __builtin_amdgcn_mfma_f32_16x16x32_bf16(a2[ks], Bc[1][ks][et], acc[1][et], 0, 0, 0);
            }
        }
        __builtin_amdgcn_s_setprio(0);

        // ---- prefetch tile g+1's A fragments ----
        if (g < 7) {
            const size_t ab = (size_t)(rg0 + (g + 1) * 2 + rh) * 2048 + lane8;
            #pragma unroll
            for (int ks = 0; ks < 4; ++ks) {
                a1[ks] = *reinterpret_cast<const bf16x8*>(X1f + ab + ks * 512);
                a2[ks] = *reinterpret_cast<const bf16x8*>(X2f + ab + ks * 512);
            }
        }

        // ---- in-register cross-mat products + DPP folds -> per-tile LDS ----
        f32x4 pd = {0.f, 0.f, 0.f, 0.f};
        f32x4 q1 = {0.f, 0.f, 0.f, 0.f};
        f32x4 q2 = {0.f, 0.f, 0.f, 0.f};
        #pragma unroll
        for (int et = 0; et < 4; ++et) {
            f32x4 c1 = acc[0][et];
            f32x4 c2 = acc[1][et];
            pd += c1 * c2;
            q1 += c1 * c1;
            q2 += c2 * c2;
        }
        pd = fold4(pd);
        q1 = fold4(q1);
        q2 = fold4(q2);

        if ((m & 3) == 0) {
            const int grp = m >> 2;
            const int rb  = rh * 16 + quad * 4;
            *reinterpret_cast<f32x4*>(&sRedAll[g][0][eh][grp][rb]) = pd;
            *reinterpret_cast<f32x4*>(&sRedAll[g][1][eh][grp][rb]) = q1;
            *reinterpret_cast<f32x4*>(&sRedAll[g][2][eh][grp][rb]) = q2;
        }
        // NO barrier here — waves drift through tiles independently.
    }

    __syncthreads();   // the ONLY barrier: all 8 tiles' partials visible

    // ---- output: thread t -> tile = t>>5, row = t&31 (n = grpN*256 + t) ----
    {
        const int tile = tid >> 5;
        const int row  = tid & 31;
        float dot = 0.f, s1 = 0.f, s2 = 0.f;
        #pragma unroll
        for (int e2 = 0; e2 < 2; ++e2)
            #pragma unroll
            for (int gg = 0; gg < 4; ++gg) {
                dot += sRedAll[tile][0][e2][gg][row];
                s1  += sRedAll[tile][1][e2][gg][row];
                s2  += sRedAll[tile][2][e2][gg][row];
            }
        float n1 = fmaxf(sqrtf(s1), EPS);
        float n2 = fmaxf(sqrtf(s2), EPS);
        float tot = dot / (n1 * n2) + p2v + bk;
        out[nOut * KK + k] = fmaxf(tot, 0.f);
    }
}

extern "C" void kernel_launch(void* const* d_in, const int* in_sizes, int n_in,
                              void* d_out, int out_size, void* d_ws, size_t ws_size,
                              hipStream_t stream) {
    const float* x1 = (const float*)d_in[0];
    const float* x2 = (const float*)d_in[1];
    const float* W1 = (const float*)d_in[2];
    const float* W2 = (const float*)d_in[3];
    const float* V  = (const float*)d_in[4];
    const float* b  = (const float*)d_in[5];
    float* out = (float*)d_out;

    const int N = in_sizes[0] / DD;   // 32768

    __bf16* X1f = (__bf16*)d_ws;
    __bf16* X2f = X1f + (size_t)N * DD;
    __bf16* W1f = X2f + (size_t)N * DD;
    __bf16* W2f = W1f + (size_t)KK * DD * DD;
    float*  p2  = (float*)(W2f + (size_t)KK * DD * DD);   // [2][N*KK]

    const int cvt_half = N / 16;                  // 2048 blocks per tensor
    const int wf_half  = KK * DD * DD / 8 / 256;  // 256
    prep_kernel<<<2 * cvt_half + 2 * wf_half, 256, 0, stream>>>(
        x1, x2, W1, W2, V, X1f, X2f, W1f, W2f, p2, cvt_half, wf_half);

    const int groups = N / 256;                   // 128
    ntn_main<<<groups * KK, 256, 0, stream>>>(X1f, X2f, W1f, W2f, p2, b, out,
                                              groups / 8, N * KK);
}

// Round 4
// 162.608 us; speedup vs baseline: 1.6723x; 1.0151x over previous
//
#include <hip/hip_runtime.h>
#include <cstdint>
#include <cstddef>

#define DD 128
#define KK 32
constexpr float EPS = 1e-8f;

typedef __bf16 bf16x8 __attribute__((ext_vector_type(8)));
typedef float f32x4 __attribute__((ext_vector_type(4)));

__device__ __forceinline__ unsigned short f2bf(float x) {
    union { float f; uint32_t u; } v; v.f = x;
    uint32_t r = v.u + 0x7FFFu + ((v.u >> 16) & 1u);   // RNE
    return (unsigned short)(r >> 16);
}
__device__ __forceinline__ __bf16 f2bf16(float x) {
    unsigned short u = f2bf(x);
    __bf16 r; __builtin_memcpy(&r, &u, 2); return r;
}
// pack 8 floats -> 8 bf16 in a uint4 (one 16B store)
__device__ __forceinline__ uint4 pack8(float4 a, float4 b) {
    uint4 o;
    o.x = (uint32_t)f2bf(a.x) | ((uint32_t)f2bf(a.y) << 16);
    o.y = (uint32_t)f2bf(a.z) | ((uint32_t)f2bf(a.w) << 16);
    o.z = (uint32_t)f2bf(b.x) | ((uint32_t)f2bf(b.y) << 16);
    o.w = (uint32_t)f2bf(b.z) | ((uint32_t)f2bf(b.w) << 16);
    return o;
}

// DPP quad_perm fold over lane-xor 1,2 (VALU pipe, no LDS).
template <int CTRL>
__device__ __forceinline__ float dpp_fold(float x) {
    union { float f; int i; } u, r;
    u.f = x;
    r.i = __builtin_amdgcn_update_dpp(0, u.i, CTRL, 0xF, 0xF, false);
    return x + r.f;
}
__device__ __forceinline__ f32x4 fold4(f32x4 v) {
    #pragma unroll
    for (int c = 0; c < 4; ++c) {
        float x = v[c];
        x = dpp_fold<0xB1>(x);   // xor 1
        x = dpp_fold<0x4E>(x);   // xor 2
        v[c] = x;
    }
    return v;
}

// ---------------- prep kernel: cvt + wf + FUSED part2 -----------------------
// cvt blocks stage 16 rows of x (f32) in LDS anyway; waves 0,1 additionally
// compute this tensor-half's part2 contribution for those 16 rows:
//   p2t[half][k][n] = x_half[n] . V[k][half*128 : half*128+128]
// via 4 MFMAs per wave (ct = wave = k-group of 16). TRANSPOSED [k][n] planes:
// each lane's 4 acc regs are 4 consecutive n -> one f32x4 store; ntn_main
// (fixed k, contiguous n) then reads each plane fully coalesced.
__global__ __launch_bounds__(256) void prep_kernel(
    const float* __restrict__ x1, const float* __restrict__ x2,
    const float* __restrict__ W1, const float* __restrict__ W2,
    const float* __restrict__ V,
    __bf16* __restrict__ X1f, __bf16* __restrict__ X2f,
    __bf16* __restrict__ W1f, __bf16* __restrict__ W2f,
    float* __restrict__ p2,            // [2][KK][N]
    int cvt_half, int wf_half)
{
    __shared__ float tile[16][132];   // 8.4 KB, +4 pad
    const int nTot = cvt_half * 16;
    int bb = blockIdx.x;
    if (bb < 2 * cvt_half) {
        const float* src; __bf16* dst; int half;
        if (bb >= cvt_half) { src = x2; dst = X2f; half = 1; bb -= cvt_half; }
        else                { src = x1; dst = X1f; half = 0; }
        const int rg = bb;
        {
            const int row = threadIdx.x >> 4;
            const int c8  = (threadIdx.x & 15) * 8;
            const float* p = src + (size_t)(rg * 16 + row) * DD + c8;
            float4 f0 = *reinterpret_cast<const float4*>(p);
            float4 f1 = *reinterpret_cast<const float4*>(p + 4);
            *reinterpret_cast<float4*>(&tile[row][c8])     = f0;
            *reinterpret_cast<float4*>(&tile[row][c8 + 4]) = f1;
        }
        __syncthreads();
        {
            const int mm = threadIdx.x & 15;
            const int c  = threadIdx.x >> 4;
            float4 a = *reinterpret_cast<float4*>(&tile[mm][c * 8]);
            float4 b = *reinterpret_cast<float4*>(&tile[mm][c * 8 + 4]);
            size_t off = (size_t)rg * 2048 + (size_t)c * 128 + (size_t)mm * 8;
            *reinterpret_cast<uint4*>(dst + off) = pack8(a, b);
        }
        // ---- fused part2 half-dot: waves 0,1 only (ct = wave) ----
        const int wave = threadIdx.x >> 6;
        if (wave < 2) {
            const int lane = threadIdx.x & 63;
            const int m    = lane & 15;
            const int quad = lane >> 4;
            const int ct   = wave;
            bf16x8 a[4], bf[4];
            #pragma unroll
            for (int ks = 0; ks < 4; ++ks) {
                // A: row m, d = ks*32 + quad*8 .. +8 (from LDS tile, f32)
                float4 a0 = *reinterpret_cast<float4*>(&tile[m][ks * 32 + quad * 8]);
                float4 a1 = *reinterpret_cast<float4*>(&tile[m][ks * 32 + quad * 8 + 4]);
                bf16x8 t;
                t[0] = f2bf16(a0.x); t[1] = f2bf16(a0.y);
                t[2] = f2bf16(a0.z); t[3] = f2bf16(a0.w);
                t[4] = f2bf16(a1.x); t[5] = f2bf16(a1.y);
                t[6] = f2bf16(a1.z); t[7] = f2bf16(a1.w);
                a[ks] = t;
                // B: col k = ct*16+m, same d-range of this half of V
                const float* Vp = V + (size_t)(ct * 16 + m) * 256 + half * 128 + ks * 32 + quad * 8;
                float4 v0 = *reinterpret_cast<const float4*>(Vp);
                float4 v1 = *reinterpret_cast<const float4*>(Vp + 4);
                bf16x8 u;
                u[0] = f2bf16(v0.x); u[1] = f2bf16(v0.y);
                u[2] = f2bf16(v0.z); u[3] = f2bf16(v0.w);
                u[4] = f2bf16(v1.x); u[5] = f2bf16(v1.y);
                u[6] = f2bf16(v1.z); u[7] = f2bf16(v1.w);
                bf[ks] = u;
            }
            f32x4 acc = {0.f, 0.f, 0.f, 0.f};
            #pragma unroll
            for (int ks = 0; ks < 4; ++ks)
                acc = __builtin_amdgcn_mfma_f32_16x16x32_bf16(a[ks], bf[ks], acc, 0, 0, 0);
            // transposed store: plane [k][n], 4 consecutive n per lane
            float* p2h = p2 + (size_t)half * KK * nTot;
            *reinterpret_cast<f32x4*>(
                &p2h[(size_t)(ct * 16 + m) * nTot + rg * 16 + quad * 4]) = acc;
        }
    } else {
        bb -= 2 * cvt_half;
        const float* W; __bf16* Wf;
        if (bb >= wf_half) { W = W2; Wf = W2f; bb -= wf_half; }
        else               { W = W1; Wf = W1f; }
        int idx = bb * 256 + threadIdx.x;
        int mm = idx & 15;
        int c  = (idx >> 4) & 15;
        int eg = (idx >> 8) & 7;
        int k  = idx >> 11;
        const float* Wk = W + (size_t)k * DD * DD;
        int e = eg * 16 + mm;
        float4 a, b;
        a.x = Wk[(size_t)(c * 8 + 0) * DD + e];
        a.y = Wk[(size_t)(c * 8 + 1) * DD + e];
        a.z = Wk[(size_t)(c * 8 + 2) * DD + e];
        a.w = Wk[(size_t)(c * 8 + 3) * DD + e];
        b.x = Wk[(size_t)(c * 8 + 4) * DD + e];
        b.y = Wk[(size_t)(c * 8 + 5) * DD + e];
        b.z = Wk[(size_t)(c * 8 + 6) * DD + e];
        b.w = Wk[(size_t)(c * 8 + 7) * DD + e];
        size_t off = ((size_t)(k * 8 + eg)) * 2048 + (size_t)c * 128 + (size_t)mm * 8;
        *reinterpret_cast<uint4*>(Wf + off) = pack8(a, b);
    }
}

// ---------------- main fused kernel: ONE barrier per block ------------------
// EXACT r0 proven structure (82.8 us; NO setprio — drift overlap is the
// mechanism, priority biasing starves the prefetching waves). Grid 4096 =
// 32 k x 128 row-groups. Block = 4 waves, wave = (rh, eh): 16 rows x 64 cols
// of BOTH mats; B register-resident; A prefetched 1 tile ahead; per-tile
// folded partials in LDS; single barrier. p2 = sum of 2 transposed planes,
// each read fully coalesced (fixed k, contiguous n).
__global__ __launch_bounds__(256, 2) void ntn_main(
    const __bf16* __restrict__ X1f, const __bf16* __restrict__ X2f,
    const __bf16* __restrict__ W1f, const __bf16* __restrict__ W2f,
    const float* __restrict__ p2, const float* __restrict__ bias,
    float* __restrict__ out, int grp_per_xcd, int nTot)
{
    __shared__ __align__(16) float sRedAll[8][3][2][4][40];   // 30.7 KB

    const int b    = blockIdx.x;
    const int xcd  = b & 7;
    const int k    = (b >> 3) & 31;
    const int grpN = xcd * grp_per_xcd + (b >> 8);   // 256-row group
    const int tid  = threadIdx.x;
    const int wave = tid >> 6;
    const int lane = tid & 63;
    const int m    = lane & 15;
    const int quad = lane >> 4;
    const int rh   = wave & 1;      // row half of the 32-row tile
    const int eh   = wave >> 1;     // column half (64 cols)

    // ---- preload this thread's part2 value (coalesced: plane[k][n]) ----
    const size_t nOut = (size_t)grpN * 256 + tid;
    const size_t p2idx = (size_t)k * nTot + nOut;
    const float p2v = p2[p2idx] + p2[p2idx + (size_t)KK * nTot];
    const float bk  = bias[k];

    const __bf16* W1p = W1f + (size_t)k * 16384;
    const __bf16* W2p = W2f + (size_t)k * 16384;

    // ---- cache BOTH B halves in registers: 2 mats x 4 ks x 4 et ----
    bf16x8 Bc[2][4][4];
    #pragma unroll
    for (int ks = 0; ks < 4; ++ks)
        #pragma unroll
        for (int et = 0; et < 4; ++et) {
            const size_t boff = (size_t)(eh * 4 + et) * 2048 + ks * 512 + lane * 8;
            Bc[0][ks][et] = *reinterpret_cast<const bf16x8*>(W1p + boff);
            Bc[1][ks][et] = *reinterpret_cast<const bf16x8*>(W2p + boff);
        }

    const int rg0 = grpN * 16;
    const size_t lane8 = (size_t)lane * 8;

    // ---- preload tile 0's A fragments ----
    bf16x8 a1[4], a2[4];
    {
        const size_t ab = (size_t)(rg0 + rh) * 2048 + lane8;
        #pragma unroll
        for (int ks = 0; ks < 4; ++ks) {
            a1[ks] = *reinterpret_cast<const bf16x8*>(X1f + ab + ks * 512);
            a2[ks] = *reinterpret_cast<const bf16x8*>(X2f + ab + ks * 512);
        }
    }

    #pragma unroll
    for (int g = 0; g < 8; ++g) {
        f32x4 acc[2][4];    // [mat][et]
        #pragma unroll
        for (int mat = 0; mat < 2; ++mat)
            #pragma unroll
            for (int et = 0; et < 4; ++et) acc[mat][et] = f32x4{0.f, 0.f, 0.f, 0.f};

        #pragma unroll
        for (int ks = 0; ks < 4; ++ks) {
            #pragma unroll
            for (int et = 0; et < 4; ++et) {
                acc[0][et] = __builtin_amdgcn_mfma_f32_16x16x32_bf16(a1[ks], Bc[0][ks][et], acc[0][et], 0, 0, 0);
                acc[1][et] = __builtin_amdgcn_mfma_f32_16x16x32_bf16(a2[ks], Bc[1][ks][et], acc[1][et], 0, 0, 0);
            }
        }

        // ---- prefetch tile g+1's A fragments ----
        if (g < 7) {
            const size_t ab = (size_t)(rg0 + (g + 1) * 2 + rh) * 2048 + lane8;
            #pragma unroll
            for (int ks = 0; ks < 4; ++ks) {
                a1[ks] = *reinterpret_cast<const bf16x8*>(X1f + ab + ks * 512);
                a2[ks] = *reinterpret_cast<const bf16x8*>(X2f + ab + ks * 512);
            }
        }

        // ---- in-register cross-mat products + DPP folds -> per-tile LDS ----
        f32x4 pd = {0.f, 0.f, 0.f, 0.f};
        f32x4 q1 = {0.f, 0.f, 0.f, 0.f};
        f32x4 q2 = {0.f, 0.f, 0.f, 0.f};
        #pragma unroll
        for (int et = 0; et < 4; ++et) {
            f32x4 c1 = acc[0][et];
            f32x4 c2 = acc[1][et];
            pd += c1 * c2;
            q1 += c1 * c1;
            q2 += c2 * c2;
        }
        pd = fold4(pd);
        q1 = fold4(q1);
        q2 = fold4(q2);

        if ((m & 3) == 0) {
            const int grp = m >> 2;
            const int rb  = rh * 16 + quad * 4;
            *reinterpret_cast<f32x4*>(&sRedAll[g][0][eh][grp][rb]) = pd;
            *reinterpret_cast<f32x4*>(&sRedAll[g][1][eh][grp][rb]) = q1;
            *reinterpret_cast<f32x4*>(&sRedAll[g][2][eh][grp][rb]) = q2;
        }
        // NO barrier here — waves drift through tiles independently.
    }

    __syncthreads();   // the ONLY barrier: all 8 tiles' partials visible

    // ---- output: thread t -> tile = t>>5, row = t&31 (n = grpN*256 + t) ----
    {
        const int tile = tid >> 5;
        const int row  = tid & 31;
        float dot = 0.f, s1 = 0.f, s2 = 0.f;
        #pragma unroll
        for (int e2 = 0; e2 < 2; ++e2)
            #pragma unroll
            for (int gg = 0; gg < 4; ++gg) {
                dot += sRedAll[tile][0][e2][gg][row];
                s1  += sRedAll[tile][1][e2][gg][row];
                s2  += sRedAll[tile][2][e2][gg][row];
            }
        float n1 = fmaxf(sqrtf(s1), EPS);
        float n2 = fmaxf(sqrtf(s2), EPS);
        float tot = dot / (n1 * n2) + p2v + bk;
        out[nOut * KK + k] = fmaxf(tot, 0.f);
    }
}

extern "C" void kernel_launch(void* const* d_in, const int* in_sizes, int n_in,
                              void* d_out, int out_size, void* d_ws, size_t ws_size,
                              hipStream_t stream) {
    const float* x1 = (const float*)d_in[0];
    const float* x2 = (const float*)d_in[1];
    const float* W1 = (const float*)d_in[2];
    const float* W2 = (const float*)d_in[3];
    const float* V  = (const float*)d_in[4];
    const float* b  = (const float*)d_in[5];
    float* out = (float*)d_out;

    const int N = in_sizes[0] / DD;   // 32768

    __bf16* X1f = (__bf16*)d_ws;
    __bf16* X2f = X1f + (size_t)N * DD;
    __bf16* W1f = X2f + (size_t)N * DD;
    __bf16* W2f = W1f + (size_t)KK * DD * DD;
    float*  p2  = (float*)(W2f + (size_t)KK * DD * DD);   // [2][KK][N]

    const int cvt_half = N / 16;                  // 2048 blocks per tensor
    const int wf_half  = KK * DD * DD / 8 / 256;  // 256
    prep_kernel<<<2 * cvt_half + 2 * wf_half, 256, 0, stream>>>(
        x1, x2, W1, W2, V, X1f, X2f, W1f, W2f, p2, cvt_half, wf_half);

    const int groups = N / 256;                   // 128
    ntn_main<<<groups * KK, 256, 0, stream>>>(X1f, X2f, W1f, W2f, p2, b, out,
                                              groups / 8, N);
}

// Round 5
// 161.924 us; speedup vs baseline: 1.6794x; 1.0042x over previous
//
#include <hip/hip_runtime.h>
#include <cstdint>
#include <cstddef>

#define DD 128
#define KK 32
constexpr float EPS = 1e-8f;

typedef __bf16 bf16x8 __attribute__((ext_vector_type(8)));
typedef float f32x4 __attribute__((ext_vector_type(4)));

__device__ __forceinline__ unsigned short f2bf(float x) {
    union { float f; uint32_t u; } v; v.f = x;
    uint32_t r = v.u + 0x7FFFu + ((v.u >> 16) & 1u);   // RNE
    return (unsigned short)(r >> 16);
}
__device__ __forceinline__ __bf16 f2bf16(float x) {
    unsigned short u = f2bf(x);
    __bf16 r; __builtin_memcpy(&r, &u, 2); return r;
}
// pack 8 floats -> 8 bf16 in a uint4 (one 16B store)
__device__ __forceinline__ uint4 pack8(float4 a, float4 b) {
    uint4 o;
    o.x = (uint32_t)f2bf(a.x) | ((uint32_t)f2bf(a.y) << 16);
    o.y = (uint32_t)f2bf(a.z) | ((uint32_t)f2bf(a.w) << 16);
    o.z = (uint32_t)f2bf(b.x) | ((uint32_t)f2bf(b.y) << 16);
    o.w = (uint32_t)f2bf(b.z) | ((uint32_t)f2bf(b.w) << 16);
    return o;
}

// DPP quad_perm fold over lane-xor 1,2 (VALU pipe, no LDS).
template <int CTRL>
__device__ __forceinline__ float dpp_fold(float x) {
    union { float f; int i; } u, r;
    u.f = x;
    r.i = __builtin_amdgcn_update_dpp(0, u.i, CTRL, 0xF, 0xF, false);
    return x + r.f;
}
__device__ __forceinline__ f32x4 fold4(f32x4 v) {
    #pragma unroll
    for (int c = 0; c < 4; ++c) {
        float x = v[c];
        x = dpp_fold<0xB1>(x);   // xor 1
        x = dpp_fold<0x4E>(x);   // xor 2
        v[c] = x;
    }
    return v;
}

// ---------------- prep kernel: cvt + wf + FUSED part2 (r4 proven) -----------
// cvt blocks stage 16 rows of x (f32) in LDS anyway; waves 0,1 additionally
// compute this tensor-half's part2 contribution for those 16 rows:
//   p2t[half][k][n] = x_half[n] . V[k][half*128 : half*128+128]
// via 4 MFMAs per wave (ct = wave = k-group of 16). TRANSPOSED [k][n] planes:
// each lane's 4 acc regs are 4 consecutive n -> one f32x4 store; ntn_main
// (fixed k, contiguous n) then reads each plane fully coalesced.
__global__ __launch_bounds__(256) void prep_kernel(
    const float* __restrict__ x1, const float* __restrict__ x2,
    const float* __restrict__ W1, const float* __restrict__ W2,
    const float* __restrict__ V,
    __bf16* __restrict__ X1f, __bf16* __restrict__ X2f,
    __bf16* __restrict__ W1f, __bf16* __restrict__ W2f,
    float* __restrict__ p2,            // [2][KK][N]
    int cvt_half, int wf_half)
{
    __shared__ float tile[16][132];   // 8.4 KB, +4 pad
    const int nTot = cvt_half * 16;
    int bb = blockIdx.x;
    if (bb < 2 * cvt_half) {
        const float* src; __bf16* dst; int half;
        if (bb >= cvt_half) { src = x2; dst = X2f; half = 1; bb -= cvt_half; }
        else                { src = x1; dst = X1f; half = 0; }
        const int rg = bb;
        {
            const int row = threadIdx.x >> 4;
            const int c8  = (threadIdx.x & 15) * 8;
            const float* p = src + (size_t)(rg * 16 + row) * DD + c8;
            float4 f0 = *reinterpret_cast<const float4*>(p);
            float4 f1 = *reinterpret_cast<const float4*>(p + 4);
            *reinterpret_cast<float4*>(&tile[row][c8])     = f0;
            *reinterpret_cast<float4*>(&tile[row][c8 + 4]) = f1;
        }
        __syncthreads();
        {
            const int mm = threadIdx.x & 15;
            const int c  = threadIdx.x >> 4;
            float4 a = *reinterpret_cast<float4*>(&tile[mm][c * 8]);
            float4 b = *reinterpret_cast<float4*>(&tile[mm][c * 8 + 4]);
            size_t off = (size_t)rg * 2048 + (size_t)c * 128 + (size_t)mm * 8;
            *reinterpret_cast<uint4*>(dst + off) = pack8(a, b);
        }
        // ---- fused part2 half-dot: waves 0,1 only (ct = wave) ----
        const int wave = threadIdx.x >> 6;
        if (wave < 2) {
            const int lane = threadIdx.x & 63;
            const int m    = lane & 15;
            const int quad = lane >> 4;
            const int ct   = wave;
            bf16x8 a[4], bf[4];
            #pragma unroll
            for (int ks = 0; ks < 4; ++ks) {
                // A: row m, d = ks*32 + quad*8 .. +8 (from LDS tile, f32)
                float4 a0 = *reinterpret_cast<float4*>(&tile[m][ks * 32 + quad * 8]);
                float4 a1 = *reinterpret_cast<float4*>(&tile[m][ks * 32 + quad * 8 + 4]);
                bf16x8 t;
                t[0] = f2bf16(a0.x); t[1] = f2bf16(a0.y);
                t[2] = f2bf16(a0.z); t[3] = f2bf16(a0.w);
                t[4] = f2bf16(a1.x); t[5] = f2bf16(a1.y);
                t[6] = f2bf16(a1.z); t[7] = f2bf16(a1.w);
                a[ks] = t;
                // B: col k = ct*16+m, same d-range of this half of V
                const float* Vp = V + (size_t)(ct * 16 + m) * 256 + half * 128 + ks * 32 + quad * 8;
                float4 v0 = *reinterpret_cast<const float4*>(Vp);
                float4 v1 = *reinterpret_cast<const float4*>(Vp + 4);
                bf16x8 u;
                u[0] = f2bf16(v0.x); u[1] = f2bf16(v0.y);
                u[2] = f2bf16(v0.z); u[3] = f2bf16(v0.w);
                u[4] = f2bf16(v1.x); u[5] = f2bf16(v1.y);
                u[6] = f2bf16(v1.z); u[7] = f2bf16(v1.w);
                bf[ks] = u;
            }
            f32x4 acc = {0.f, 0.f, 0.f, 0.f};
            #pragma unroll
            for (int ks = 0; ks < 4; ++ks)
                acc = __builtin_amdgcn_mfma_f32_16x16x32_bf16(a[ks], bf[ks], acc, 0, 0, 0);
            // transposed store: plane [k][n], 4 consecutive n per lane
            float* p2h = p2 + (size_t)half * KK * nTot;
            *reinterpret_cast<f32x4*>(
                &p2h[(size_t)(ct * 16 + m) * nTot + rg * 16 + quad * 4]) = acc;
        }
    } else {
        bb -= 2 * cvt_half;
        const float* W; __bf16* Wf;
        if (bb >= wf_half) { W = W2; Wf = W2f; bb -= wf_half; }
        else               { W = W1; Wf = W1f; }
        int idx = bb * 256 + threadIdx.x;
        int mm = idx & 15;
        int c  = (idx >> 4) & 15;
        int eg = (idx >> 8) & 7;
        int k  = idx >> 11;
        const float* Wk = W + (size_t)k * DD * DD;
        int e = eg * 16 + mm;
        float4 a, b;
        a.x = Wk[(size_t)(c * 8 + 0) * DD + e];
        a.y = Wk[(size_t)(c * 8 + 1) * DD + e];
        a.z = Wk[(size_t)(c * 8 + 2) * DD + e];
        a.w = Wk[(size_t)(c * 8 + 3) * DD + e];
        b.x = Wk[(size_t)(c * 8 + 4) * DD + e];
        b.y = Wk[(size_t)(c * 8 + 5) * DD + e];
        b.z = Wk[(size_t)(c * 8 + 6) * DD + e];
        b.w = Wk[(size_t)(c * 8 + 7) * DD + e];
        size_t off = ((size_t)(k * 8 + eg)) * 2048 + (size_t)c * 128 + (size_t)mm * 8;
        *reinterpret_cast<uint4*>(Wf + off) = pack8(a, b);
    }
}

// ---------------- main fused kernel: 512 rows/block, 2 phases ---------------
// Grid 2048 = 32 k x 64 row-groups (512 rows). XCD decode: xcd=b&7,
// k=(b>>3)&31, group per-XCD. Block = 4 waves, wave = (rh, eh): 16 rows x
// 64 cols of BOTH mats; B register-resident (one 32-load prologue now
// amortized over 512 rows = 2x previous); A prefetched 1 tile ahead with the
// chain running across the phase boundary. Two phases of 8 tiles each reuse
// the same 30.7 KB sRed slab: phase g-loops are barrier-free (waves drift;
// MFMA of one wave overlaps epilogue VALU of another), with barriers only at
// phase edges. p2/bias loads live in the epilogues (register diet for the
// main loop -> more of Bc stays resident under the 2-wave/SIMD reg cap).
__global__ __launch_bounds__(256, 2) void ntn_main(
    const __bf16* __restrict__ X1f, const __bf16* __restrict__ X2f,
    const __bf16* __restrict__ W1f, const __bf16* __restrict__ W2f,
    const float* __restrict__ p2, const float* __restrict__ bias,
    float* __restrict__ out, int grp_per_xcd, int nTot)
{
    __shared__ __align__(16) float sRedAll[8][3][2][4][40];   // 30.7 KB

    const int b    = blockIdx.x;
    const int xcd  = b & 7;
    const int k    = (b >> 3) & 31;
    const int grpN = xcd * grp_per_xcd + (b >> 8);   // 512-row group
    const int tid  = threadIdx.x;
    const int wave = tid >> 6;
    const int lane = tid & 63;
    const int m    = lane & 15;
    const int quad = lane >> 4;
    const int rh   = wave & 1;      // row half of the 32-row tile
    const int eh   = wave >> 1;     // column half (64 cols)

    const float bk = bias[k];       // scalar, SGPR

    const __bf16* W1p = W1f + (size_t)k * 16384;
    const __bf16* W2p = W2f + (size_t)k * 16384;

    // ---- cache BOTH B halves in registers: 2 mats x 4 ks x 4 et ----
    bf16x8 Bc[2][4][4];
    #pragma unroll
    for (int ks = 0; ks < 4; ++ks)
        #pragma unroll
        for (int et = 0; et < 4; ++et) {
            const size_t boff = (size_t)(eh * 4 + et) * 2048 + ks * 512 + lane * 8;
            Bc[0][ks][et] = *reinterpret_cast<const bf16x8*>(W1p + boff);
            Bc[1][ks][et] = *reinterpret_cast<const bf16x8*>(W2p + boff);
        }

    const int rg0 = grpN * 32;      // 32 row-groups of 16 = 512 rows
    const size_t lane8 = (size_t)lane * 8;

    // ---- preload tile 0's A fragments ----
    bf16x8 a1[4], a2[4];
    {
        const size_t ab = (size_t)(rg0 + rh) * 2048 + lane8;
        #pragma unroll
        for (int ks = 0; ks < 4; ++ks) {
            a1[ks] = *reinterpret_cast<const bf16x8*>(X1f + ab + ks * 512);
            a2[ks] = *reinterpret_cast<const bf16x8*>(X2f + ab + ks * 512);
        }
    }

    #pragma unroll
    for (int h = 0; h < 2; ++h) {
        #pragma unroll
        for (int g = 0; g < 8; ++g) {
            const int t = h * 8 + g;
            f32x4 acc[2][4];    // [mat][et]
            #pragma unroll
            for (int mat = 0; mat < 2; ++mat)
                #pragma unroll
                for (int et = 0; et < 4; ++et) acc[mat][et] = f32x4{0.f, 0.f, 0.f, 0.f};

            #pragma unroll
            for (int ks = 0; ks < 4; ++ks) {
                #pragma unroll
                for (int et = 0; et < 4; ++et) {
                    acc[0][et] = __builtin_amdgcn_mfma_f32_16x16x32_bf16(a1[ks], Bc[0][ks][et], acc[0][et], 0, 0, 0);
                    acc[1][et] = __builtin_amdgcn_mfma_f32_16x16x32_bf16(a2[ks], Bc[1][ks][et], acc[1][et], 0, 0, 0);
                }
            }

            // ---- prefetch tile t+1's A fragments (chain crosses phases) ----
            if (t < 15) {
                const size_t ab = (size_t)(rg0 + (t + 1) * 2 + rh) * 2048 + lane8;
                #pragma unroll
                for (int ks = 0; ks < 4; ++ks) {
                    a1[ks] = *reinterpret_cast<const bf16x8*>(X1f + ab + ks * 512);
                    a2[ks] = *reinterpret_cast<const bf16x8*>(X2f + ab + ks * 512);
                }
            }

            // ---- in-register cross-mat products + DPP folds -> LDS slice ----
            f32x4 pd = {0.f, 0.f, 0.f, 0.f};
            f32x4 q1 = {0.f, 0.f, 0.f, 0.f};
            f32x4 q2 = {0.f, 0.f, 0.f, 0.f};
            #pragma unroll
            for (int et = 0; et < 4; ++et) {
                f32x4 c1 = acc[0][et];
                f32x4 c2 = acc[1][et];
                pd += c1 * c2;
                q1 += c1 * c1;
                q2 += c2 * c2;
            }
            pd = fold4(pd);
            q1 = fold4(q1);
            q2 = fold4(q2);

            if ((m & 3) == 0) {
                const int grp = m >> 2;
                const int rb  = rh * 16 + quad * 4;
                *reinterpret_cast<f32x4*>(&sRedAll[g][0][eh][grp][rb]) = pd;
                *reinterpret_cast<f32x4*>(&sRedAll[g][1][eh][grp][rb]) = q1;
                *reinterpret_cast<f32x4*>(&sRedAll[g][2][eh][grp][rb]) = q2;
            }
            // NO barrier inside the phase — waves drift through tiles.
        }

        __syncthreads();   // phase barrier: all 8 tiles' partials visible

        // ---- epilogue h: thread t -> tile = t>>5, row = t&31 --------------
        {
            const int tile = tid >> 5;
            const int row  = tid & 31;
            const size_t nOut = (size_t)grpN * 512 + h * 256 + tile * 32 + row;
            const size_t p2idx = (size_t)k * nTot + nOut;
            const float p2v = p2[p2idx] + p2[p2idx + (size_t)KK * nTot];
            float dot = 0.f, s1 = 0.f, s2 = 0.f;
            #pragma unroll
            for (int e2 = 0; e2 < 2; ++e2)
                #pragma unroll
                for (int gg = 0; gg < 4; ++gg) {
                    dot += sRedAll[tile][0][e2][gg][row];
                    s1  += sRedAll[tile][1][e2][gg][row];
                    s2  += sRedAll[tile][2][e2][gg][row];
                }
            float n1 = fmaxf(sqrtf(s1), EPS);
            float n2 = fmaxf(sqrtf(s2), EPS);
            float tot = dot / (n1 * n2) + p2v + bk;
            out[nOut * KK + k] = fmaxf(tot, 0.f);
        }

        if (h == 0) __syncthreads();   // sRed reuse guard before phase 1
    }
}

extern "C" void kernel_launch(void* const* d_in, const int* in_sizes, int n_in,
                              void* d_out, int out_size, void* d_ws, size_t ws_size,
                              hipStream_t stream) {
    const float* x1 = (const float*)d_in[0];
    const float* x2 = (const float*)d_in[1];
    const float* W1 = (const float*)d_in[2];
    const float* W2 = (const float*)d_in[3];
    const float* V  = (const float*)d_in[4];
    const float* b  = (const float*)d_in[5];
    float* out = (float*)d_out;

    const int N = in_sizes[0] / DD;   // 32768

    __bf16* X1f = (__bf16*)d_ws;
    __bf16* X2f = X1f + (size_t)N * DD;
    __bf16* W1f = X2f + (size_t)N * DD;
    __bf16* W2f = W1f + (size_t)KK * DD * DD;
    float*  p2  = (float*)(W2f + (size_t)KK * DD * DD);   // [2][KK][N]

    const int cvt_half = N / 16;                  // 2048 blocks per tensor
    const int wf_half  = KK * DD * DD / 8 / 256;  // 256
    prep_kernel<<<2 * cvt_half + 2 * wf_half, 256, 0, stream>>>(
        x1, x2, W1, W2, V, X1f, X2f, W1f, W2f, p2, cvt_half, wf_half);

    const int groups = N / 512;                   // 64
    ntn_main<<<groups * KK, 256, 0, stream>>>(X1f, X2f, W1f, W2f, p2, b, out,
                                              groups / 8, N);
}

// Round 6
// 159.968 us; speedup vs baseline: 1.6999x; 1.0122x over previous
//
#include <hip/hip_runtime.h>
#include <cstdint>
#include <cstddef>

#define DD 128
#define KK 32
constexpr float EPS = 1e-8f;

typedef __bf16 bf16x8 __attribute__((ext_vector_type(8)));
typedef float f32x4 __attribute__((ext_vector_type(4)));

__device__ __forceinline__ unsigned short f2bf(float x) {
    union { float f; uint32_t u; } v; v.f = x;
    uint32_t r = v.u + 0x7FFFu + ((v.u >> 16) & 1u);   // RNE
    return (unsigned short)(r >> 16);
}
__device__ __forceinline__ __bf16 f2bf16(float x) {
    unsigned short u = f2bf(x);
    __bf16 r; __builtin_memcpy(&r, &u, 2); return r;
}
// pack 8 floats -> 8 bf16 in a uint4 (one 16B store)
__device__ __forceinline__ uint4 pack8(float4 a, float4 b) {
    uint4 o;
    o.x = (uint32_t)f2bf(a.x) | ((uint32_t)f2bf(a.y) << 16);
    o.y = (uint32_t)f2bf(a.z) | ((uint32_t)f2bf(a.w) << 16);
    o.z = (uint32_t)f2bf(b.x) | ((uint32_t)f2bf(b.y) << 16);
    o.w = (uint32_t)f2bf(b.z) | ((uint32_t)f2bf(b.w) << 16);
    return o;
}

// DPP quad_perm fold over lane-xor 1 only (VALU pipe, no LDS).
template <int CTRL>
__device__ __forceinline__ float dpp_fold(float x) {
    union { float f; int i; } u, r;
    u.f = x;
    r.i = __builtin_amdgcn_update_dpp(0, u.i, CTRL, 0xF, 0xF, false);
    return x + r.f;
}
__device__ __forceinline__ f32x4 fold1(f32x4 v) {
    #pragma unroll
    for (int c = 0; c < 4; ++c) v[c] = dpp_fold<0xB1>(v[c]);   // xor 1
    return v;
}

// ---------------- prep kernel: cvt + wf + FUSED part2 (r4 proven) -----------
__global__ __launch_bounds__(256) void prep_kernel(
    const float* __restrict__ x1, const float* __restrict__ x2,
    const float* __restrict__ W1, const float* __restrict__ W2,
    const float* __restrict__ V,
    __bf16* __restrict__ X1f, __bf16* __restrict__ X2f,
    __bf16* __restrict__ W1f, __bf16* __restrict__ W2f,
    float* __restrict__ p2,            // [2][KK][N]
    int cvt_half, int wf_half)
{
    __shared__ float tile[16][132];   // 8.4 KB, +4 pad
    const int nTot = cvt_half * 16;
    int bb = blockIdx.x;
    if (bb < 2 * cvt_half) {
        const float* src; __bf16* dst; int half;
        if (bb >= cvt_half) { src = x2; dst = X2f; half = 1; bb -= cvt_half; }
        else                { src = x1; dst = X1f; half = 0; }
        const int rg = bb;
        {
            const int row = threadIdx.x >> 4;
            const int c8  = (threadIdx.x & 15) * 8;
            const float* p = src + (size_t)(rg * 16 + row) * DD + c8;
            float4 f0 = *reinterpret_cast<const float4*>(p);
            float4 f1 = *reinterpret_cast<const float4*>(p + 4);
            *reinterpret_cast<float4*>(&tile[row][c8])     = f0;
            *reinterpret_cast<float4*>(&tile[row][c8 + 4]) = f1;
        }
        __syncthreads();
        {
            const int mm = threadIdx.x & 15;
            const int c  = threadIdx.x >> 4;
            float4 a = *reinterpret_cast<float4*>(&tile[mm][c * 8]);
            float4 b = *reinterpret_cast<float4*>(&tile[mm][c * 8 + 4]);
            size_t off = (size_t)rg * 2048 + (size_t)c * 128 + (size_t)mm * 8;
            *reinterpret_cast<uint4*>(dst + off) = pack8(a, b);
        }
        // ---- fused part2 half-dot: waves 0,1 only (ct = wave) ----
        const int wave = threadIdx.x >> 6;
        if (wave < 2) {
            const int lane = threadIdx.x & 63;
            const int m    = lane & 15;
            const int quad = lane >> 4;
            const int ct   = wave;
            bf16x8 a[4], bf[4];
            #pragma unroll
            for (int ks = 0; ks < 4; ++ks) {
                float4 a0 = *reinterpret_cast<float4*>(&tile[m][ks * 32 + quad * 8]);
                float4 a1 = *reinterpret_cast<float4*>(&tile[m][ks * 32 + quad * 8 + 4]);
                bf16x8 t;
                t[0] = f2bf16(a0.x); t[1] = f2bf16(a0.y);
                t[2] = f2bf16(a0.z); t[3] = f2bf16(a0.w);
                t[4] = f2bf16(a1.x); t[5] = f2bf16(a1.y);
                t[6] = f2bf16(a1.z); t[7] = f2bf16(a1.w);
                a[ks] = t;
                const float* Vp = V + (size_t)(ct * 16 + m) * 256 + half * 128 + ks * 32 + quad * 8;
                float4 v0 = *reinterpret_cast<const float4*>(Vp);
                float4 v1 = *reinterpret_cast<const float4*>(Vp + 4);
                bf16x8 u;
                u[0] = f2bf16(v0.x); u[1] = f2bf16(v0.y);
                u[2] = f2bf16(v0.z); u[3] = f2bf16(v0.w);
                u[4] = f2bf16(v1.x); u[5] = f2bf16(v1.y);
                u[6] = f2bf16(v1.z); u[7] = f2bf16(v1.w);
                bf[ks] = u;
            }
            f32x4 acc = {0.f, 0.f, 0.f, 0.f};
            #pragma unroll
            for (int ks = 0; ks < 4; ++ks)
                acc = __builtin_amdgcn_mfma_f32_16x16x32_bf16(a[ks], bf[ks], acc, 0, 0, 0);
            float* p2h = p2 + (size_t)half * KK * nTot;
            *reinterpret_cast<f32x4*>(
                &p2h[(size_t)(ct * 16 + m) * nTot + rg * 16 + quad * 4]) = acc;
        }
    } else {
        bb -= 2 * cvt_half;
        const float* W; __bf16* Wf;
        if (bb >= wf_half) { W = W2; Wf = W2f; bb -= wf_half; }
        else               { W = W1; Wf = W1f; }
        int idx = bb * 256 + threadIdx.x;
        int mm = idx & 15;
        int c  = (idx >> 4) & 15;
        int eg = (idx >> 8) & 7;
        int k  = idx >> 11;
        const float* Wk = W + (size_t)k * DD * DD;
        int e = eg * 16 + mm;
        float4 a, b;
        a.x = Wk[(size_t)(c * 8 + 0) * DD + e];
        a.y = Wk[(size_t)(c * 8 + 1) * DD + e];
        a.z = Wk[(size_t)(c * 8 + 2) * DD + e];
        a.w = Wk[(size_t)(c * 8 + 3) * DD + e];
        b.x = Wk[(size_t)(c * 8 + 4) * DD + e];
        b.y = Wk[(size_t)(c * 8 + 5) * DD + e];
        b.z = Wk[(size_t)(c * 8 + 6) * DD + e];
        b.w = Wk[(size_t)(c * 8 + 7) * DD + e];
        size_t off = ((size_t)(k * 8 + eg)) * 2048 + (size_t)c * 128 + (size_t)mm * 8;
        *reinterpret_cast<uint4*>(Wf + off) = pack8(a, b);
    }
}

// ---------------- main fused kernel: 256 rows/block, VALU-diet g-loop -------
// r4 structure (grid 4096 = 32 k x 128 groups, ONE barrier) with two cuts to
// the per-tile VALU tax that capped MfmaUtil:
//  1. no per-tile acc zero-init: ks=0 MFMAs take a hoisted zero quad as C
//     (saves 32 accvgpr_write per tile).
//  2. single DPP fold (xor1 only; saves 24 instr/tile); partials stored 2x
//     wide ((m&1)==0 lanes, 8 groups) into sRed[8][3][2][8][40] = 61.4 KB
//     (2 blocks/CU at 122.9 KB); the extra adds move to the once-per-block
//     epilogue where all 256 threads parallelize them.
__global__ __launch_bounds__(256, 2) void ntn_main(
    const __bf16* __restrict__ X1f, const __bf16* __restrict__ X2f,
    const __bf16* __restrict__ W1f, const __bf16* __restrict__ W2f,
    const float* __restrict__ p2, const float* __restrict__ bias,
    float* __restrict__ out, int grp_per_xcd, int nTot)
{
    __shared__ __align__(16) float sRedAll[8][3][2][8][40];   // 61.4 KB

    const int b    = blockIdx.x;
    const int xcd  = b & 7;
    const int k    = (b >> 3) & 31;
    const int grpN = xcd * grp_per_xcd + (b >> 8);   // 256-row group
    const int tid  = threadIdx.x;
    const int wave = tid >> 6;
    const int lane = tid & 63;
    const int m    = lane & 15;
    const int quad = lane >> 4;
    const int rh   = wave & 1;      // row half of the 32-row tile
    const int eh   = wave >> 1;     // column half (64 cols)

    const __bf16* W1p = W1f + (size_t)k * 16384;
    const __bf16* W2p = W2f + (size_t)k * 16384;

    // ---- cache BOTH B halves in registers: 2 mats x 4 ks x 4 et ----
    bf16x8 Bc[2][4][4];
    #pragma unroll
    for (int ks = 0; ks < 4; ++ks)
        #pragma unroll
        for (int et = 0; et < 4; ++et) {
            const size_t boff = (size_t)(eh * 4 + et) * 2048 + ks * 512 + lane * 8;
            Bc[0][ks][et] = *reinterpret_cast<const bf16x8*>(W1p + boff);
            Bc[1][ks][et] = *reinterpret_cast<const bf16x8*>(W2p + boff);
        }

    const int rg0 = grpN * 16;
    const size_t lane8 = (size_t)lane * 8;

    // ---- preload tile 0's A fragments ----
    bf16x8 a1[4], a2[4];
    {
        const size_t ab = (size_t)(rg0 + rh) * 2048 + lane8;
        #pragma unroll
        for (int ks = 0; ks < 4; ++ks) {
            a1[ks] = *reinterpret_cast<const bf16x8*>(X1f + ab + ks * 512);
            a2[ks] = *reinterpret_cast<const bf16x8*>(X2f + ab + ks * 512);
        }
    }

    const f32x4 z = {0.f, 0.f, 0.f, 0.f};   // hoisted zero quad (C of ks=0)

    #pragma unroll
    for (int g = 0; g < 8; ++g) {
        f32x4 acc[2][4];    // [mat][et] — written by ks=0 MFMA, no init
        #pragma unroll
        for (int et = 0; et < 4; ++et) {
            acc[0][et] = __builtin_amdgcn_mfma_f32_16x16x32_bf16(a1[0], Bc[0][0][et], z, 0, 0, 0);
            acc[1][et] = __builtin_amdgcn_mfma_f32_16x16x32_bf16(a2[0], Bc[1][0][et], z, 0, 0, 0);
        }
        #pragma unroll
        for (int ks = 1; ks < 4; ++ks) {
            #pragma unroll
            for (int et = 0; et < 4; ++et) {
                acc[0][et] = __builtin_amdgcn_mfma_f32_16x16x32_bf16(a1[ks], Bc[0][ks][et], acc[0][et], 0, 0, 0);
                acc[1][et] = __builtin_amdgcn_mfma_f32_16x16x32_bf16(a2[ks], Bc[1][ks][et], acc[1][et], 0, 0, 0);
            }
        }

        // ---- prefetch tile g+1's A fragments ----
        if (g < 7) {
            const size_t ab = (size_t)(rg0 + (g + 1) * 2 + rh) * 2048 + lane8;
            #pragma unroll
            for (int ks = 0; ks < 4; ++ks) {
                a1[ks] = *reinterpret_cast<const bf16x8*>(X1f + ab + ks * 512);
                a2[ks] = *reinterpret_cast<const bf16x8*>(X2f + ab + ks * 512);
            }
        }

        // ---- in-register cross-mat products + ONE DPP fold -> LDS slice ----
        f32x4 pd = {0.f, 0.f, 0.f, 0.f};
        f32x4 q1 = {0.f, 0.f, 0.f, 0.f};
        f32x4 q2 = {0.f, 0.f, 0.f, 0.f};
        #pragma unroll
        for (int et = 0; et < 4; ++et) {
            f32x4 c1 = acc[0][et];
            f32x4 c2 = acc[1][et];
            pd += c1 * c2;
            q1 += c1 * c1;
            q2 += c2 * c2;
        }
        pd = fold1(pd);
        q1 = fold1(q1);
        q2 = fold1(q2);

        if ((m & 1) == 0) {
            const int grp = m >> 1;          // 8 groups of 2 cols
            const int rb  = rh * 16 + quad * 4;
            *reinterpret_cast<f32x4*>(&sRedAll[g][0][eh][grp][rb]) = pd;
            *reinterpret_cast<f32x4*>(&sRedAll[g][1][eh][grp][rb]) = q1;
            *reinterpret_cast<f32x4*>(&sRedAll[g][2][eh][grp][rb]) = q2;
        }
        // NO barrier here — waves drift through tiles independently.
    }

    __syncthreads();   // the ONLY barrier: all 8 tiles' partials visible

    // ---- output: thread t -> tile = t>>5, row = t&31 (n = grpN*256 + t) ----
    {
        const int tile = tid >> 5;
        const int row  = tid & 31;
        const size_t nOut = (size_t)grpN * 256 + tid;
        const size_t p2idx = (size_t)k * nTot + nOut;
        const float p2v = p2[p2idx] + p2[p2idx + (size_t)KK * nTot];
        const float bk  = bias[k];
        float dot = 0.f, s1 = 0.f, s2 = 0.f;
        #pragma unroll
        for (int e2 = 0; e2 < 2; ++e2)
            #pragma unroll
            for (int gg = 0; gg < 8; ++gg) {
                dot += sRedAll[tile][0][e2][gg][row];
                s1  += sRedAll[tile][1][e2][gg][row];
                s2  += sRedAll[tile][2][e2][gg][row];
            }
        float n1 = fmaxf(sqrtf(s1), EPS);
        float n2 = fmaxf(sqrtf(s2), EPS);
        float tot = dot / (n1 * n2) + p2v + bk;
        out[nOut * KK + k] = fmaxf(tot, 0.f);
    }
}

extern "C" void kernel_launch(void* const* d_in, const int* in_sizes, int n_in,
                              void* d_out, int out_size, void* d_ws, size_t ws_size,
                              hipStream_t stream) {
    const float* x1 = (const float*)d_in[0];
    const float* x2 = (const float*)d_in[1];
    const float* W1 = (const float*)d_in[2];
    const float* W2 = (const float*)d_in[3];
    const float* V  = (const float*)d_in[4];
    const float* b  = (const float*)d_in[5];
    float* out = (float*)d_out;

    const int N = in_sizes[0] / DD;   // 32768

    __bf16* X1f = (__bf16*)d_ws;
    __bf16* X2f = X1f + (size_t)N * DD;
    __bf16* W1f = X2f + (size_t)N * DD;
    __bf16* W2f = W1f + (size_t)KK * DD * DD;
    float*  p2  = (float*)(W2f + (size_t)KK * DD * DD);   // [2][KK][N]

    const int cvt_half = N / 16;                  // 2048 blocks per tensor
    const int wf_half  = KK * DD * DD / 8 / 256;  // 256
    prep_kernel<<<2 * cvt_half + 2 * wf_half, 256, 0, stream>>>(
        x1, x2, W1, W2, V, X1f, X2f, W1f, W2f, p2, cvt_half, wf_half);

    const int groups = N / 256;                   // 128
    ntn_main<<<groups * KK, 256, 0, stream>>>(X1f, X2f, W1f, W2f, p2, b, out,
                                              groups / 8, N);
}